// Round 11
// baseline (155.901 us; speedup 1.0000x reference)
//
#include <hip/hip_runtime.h>
#include <math.h>

#define EMB 512
#define VQ 32
#define MCODES 32   // 2*LOG2
#define EPS 1e-8f

// ---------------------------------------------------------------------------
// prep: normalize codebook rows, G = 2*En, q = ||En||^2, C = En @ W_inv
// ---------------------------------------------------------------------------
__global__ __launch_bounds__(256)
void prep_kernel(const float* __restrict__ emb, const float* __restrict__ W_inv,
                 float* __restrict__ Cw, float* __restrict__ G, float* __restrict__ qv,
                 float* __restrict__ loss_out) {
  const int b = blockIdx.x;
  const int tid = threadIdx.x;
  __shared__ float En_s[VQ];
  float ss = 0.f;
#pragma unroll
  for (int d = 0; d < VQ; ++d) { float v = emb[b * VQ + d]; ss += v * v; }
  const float inv = 1.0f / (sqrtf(ss) + EPS);
  if (tid < VQ) En_s[tid] = emb[b * VQ + tid] * inv;
  __syncthreads();
  float a0 = 0.f, a1 = 0.f;
#pragma unroll 8
  for (int d = 0; d < VQ; ++d) {
    const float en = En_s[d];
    const float2 wv = ((const float2*)(W_inv + d * EMB))[tid];
    a0 += en * wv.x;
    a1 += en * wv.y;
  }
  ((float2*)(Cw + b * EMB))[tid] = make_float2(a0, a1);
  if (tid < VQ) G[b * VQ + tid] = 2.0f * En_s[tid];
  if (tid == 0) {
    float qq = 0.f;
#pragma unroll
    for (int d = 0; d < VQ; ++d) qq += En_s[d] * En_s[d];
    qv[b] = qq;
    if (b == 0) loss_out[0] = 0.0f;   // vq_loss
  }
}

// ---------------------------------------------------------------------------
// proj v5: barrier-free wave-local stage-then-compute.
// Each wave owns 8 tokens. h staged per 128B/row chunk through a 1KB LDS
// double buffer (128B-coalesced global loads vs R9's 16B slivers).
// Split-K is INTRA-wave: lane = (kq<<4)|(s<<3)|dg; kq handles e4 = 4j+kq
// (interleaved), combined via 2 shfl_xor. No __syncthreads anywhere.
// LDS 8KB/block (R9's 18.4KB capped occupancy at ~3 blocks/CU under the
// ~64KB/CU scheduling window). Epilogue redistributes hn via the same LDS
// slice within the wave; each lane owns 2 complete softmax pairs.
// ---------------------------------------------------------------------------
__global__ __launch_bounds__(256, 6)
void proj_kernel(const float* __restrict__ h, const int* __restrict__ mask,
                 const float* __restrict__ W_proj, const float* __restrict__ b_proj,
                 const float* __restrict__ G, const float* __restrict__ qv,
                 float* __restrict__ Aout, float* __restrict__ code_out) {
  const int tid = threadIdx.x;
  const int w = tid >> 6;        // wave 0..3
  const int lane = tid & 63;
  const int kq = lane >> 4;      // 0..3 : K-interleave slice
  const int s = (lane >> 3) & 1; // 0..1 : token-group (4 tokens each)
  const int dg = lane & 7;       // 0..7 : out-dims 4*dg..4*dg+3
  const int wtok = blockIdx.x * 32 + w * 8;   // wave's first token

  __shared__ float4 hbuf[4][2][64];   // [wave][buf][row*8+f4] : 1KB per buf

  const float4* __restrict__ h4 = (const float4*)h;
  const float4* __restrict__ W4 = (const float4*)W_proj;   // [512][8] float4

  // staging lane mapping: row = lane>>3 (0..7), f4-in-chunk = lane&7
  const float4* hsrc = h4 + (size_t)(wtok + (lane >> 3)) * (EMB / 4) + (lane & 7);

  float4 acc0 = make_float4(0.f, 0.f, 0.f, 0.f), acc1 = acc0, acc2 = acc0, acc3 = acc0;

  // prologue: stage chunk 0
  hbuf[w][0][lane] = hsrc[0];

#define ACC4(A, V)                                                        \
    A.x += V.x * w0.x; A.x += V.y * w1.x; A.x += V.z * w2.x; A.x += V.w * w3.x; \
    A.y += V.x * w0.y; A.y += V.y * w1.y; A.y += V.z * w2.y; A.y += V.w * w3.y; \
    A.z += V.x * w0.z; A.z += V.y * w1.z; A.z += V.z * w2.z; A.z += V.w * w3.z; \
    A.w += V.x * w0.w; A.w += V.y * w1.w; A.w += V.z * w2.w; A.w += V.w * w3.w;

  int b = 0;
  for (int c = 0; c < 16; ++c) {
    float4 gn;
    if (c + 1 < 16) gn = hsrc[(c + 1) * 8];     // issue-early (T14)
#pragma unroll
    for (int j = 0; j < 2; ++j) {
      const int e4l = 4 * j + kq;               // 0..7 within chunk
      const int e4 = c * 8 + e4l;               // global f4-index along e
      const float4 v0 = hbuf[w][b][(4 * s + 0) * 8 + e4l];
      const float4 v1 = hbuf[w][b][(4 * s + 1) * 8 + e4l];
      const float4 v2 = hbuf[w][b][(4 * s + 2) * 8 + e4l];
      const float4 v3 = hbuf[w][b][(4 * s + 3) * 8 + e4l];
      const float4 w0 = W4[(e4 * 4 + 0) * 8 + dg];
      const float4 w1 = W4[(e4 * 4 + 1) * 8 + dg];
      const float4 w2 = W4[(e4 * 4 + 2) * 8 + dg];
      const float4 w3 = W4[(e4 * 4 + 3) * 8 + dg];
      ACC4(acc0, v0) ACC4(acc1, v1) ACC4(acc2, v2) ACC4(acc3, v3)
    }
    if (c + 1 < 16) hbuf[w][b ^ 1][lane] = gn;  // write-late
    b ^= 1;
  }
#undef ACC4

  // combine split-K partials across kq lanes: (k0+k1)+(k2+k3)
#define CMB(A) \
  A.x += __shfl_xor(A.x, 16); A.y += __shfl_xor(A.y, 16); \
  A.z += __shfl_xor(A.z, 16); A.w += __shfl_xor(A.w, 16); \
  A.x += __shfl_xor(A.x, 32); A.y += __shfl_xor(A.y, 32); \
  A.z += __shfl_xor(A.z, 32); A.w += __shfl_xor(A.w, 32);
  CMB(acc0) CMB(acc1) CMB(acc2) CMB(acc3)
#undef CMB

  // bias
  const float4 bp = ((const float4*)b_proj)[dg];
  acc0.x += bp.x; acc0.y += bp.y; acc0.z += bp.z; acc0.w += bp.w;
  acc1.x += bp.x; acc1.y += bp.y; acc1.z += bp.z; acc1.w += bp.w;
  acc2.x += bp.x; acc2.y += bp.y; acc2.z += bp.z; acc2.w += bp.w;
  acc3.x += bp.x; acc3.y += bp.y; acc3.z += bp.z; acc3.w += bp.w;

  // per-token ||hp||^2: within-lane + across the 8 dg lanes
  float ss0 = acc0.x * acc0.x + acc0.y * acc0.y + acc0.z * acc0.z + acc0.w * acc0.w;
  float ss1 = acc1.x * acc1.x + acc1.y * acc1.y + acc1.z * acc1.z + acc1.w * acc1.w;
  float ss2 = acc2.x * acc2.x + acc2.y * acc2.y + acc2.z * acc2.z + acc2.w * acc2.w;
  float ss3 = acc3.x * acc3.x + acc3.y * acc3.y + acc3.z * acc3.z + acc3.w * acc3.w;
#pragma unroll
  for (int m = 1; m <= 4; m <<= 1) {
    ss0 += __shfl_xor(ss0, m); ss1 += __shfl_xor(ss1, m);
    ss2 += __shfl_xor(ss2, m); ss3 += __shfl_xor(ss3, m);
  }
  const float i0 = 1.0f / (sqrtf(ss0) + EPS);
  const float i1 = 1.0f / (sqrtf(ss1) + EPS);
  const float i2 = 1.0f / (sqrtf(ss2) + EPS);
  const float i3 = 1.0f / (sqrtf(ss3) + EPS);
  acc0.x *= i0; acc0.y *= i0; acc0.z *= i0; acc0.w *= i0;
  acc1.x *= i1; acc1.y *= i1; acc1.z *= i1; acc1.w *= i1;
  acc2.x *= i2; acc2.y *= i2; acc2.z *= i2; acc2.w *= i2;
  acc3.x *= i3; acc3.y *= i3; acc3.z *= i3; acc3.w *= i3;

  // redistribute hn through the wave's LDS slice (reads of hbuf all retired)
  float* scratch = (float*)&hbuf[w][0][0];    // 2KB; layout [tok][40] floats
  if (kq == 0) {
    *(float4*)&scratch[(4 * s + 0) * 40 + 4 * dg] = acc0;
    *(float4*)&scratch[(4 * s + 1) * 40 + 4 * dg] = acc1;
    *(float4*)&scratch[(4 * s + 2) * 40 + 4 * dg] = acc2;
    *(float4*)&scratch[(4 * s + 3) * 40 + 4 * dg] = acc3;
  }
  // re-map: lane = tk*8 + pg ; tk owns token wtok+tk, pg owns codes 4pg..4pg+3
  const int tk = lane >> 3;
  const int pg = lane & 7;
  float4 hn[8];
#pragma unroll
  for (int k = 0; k < 8; ++k) hn[k] = *(const float4*)&scratch[tk * 40 + 4 * k];

  const float4* G4 = (const float4*)G;        // [32][8] float4, rows = 2*En_m
  float sc[4];
#pragma unroll
  for (int m4 = 0; m4 < 4; ++m4) {
    const int m = 4 * pg + m4;
    float d = 0.f;
#pragma unroll
    for (int k = 0; k < 8; ++k) {
      const float4 g = G4[m * 8 + k];
      const float4 v = hn[k];
      d += v.x * g.x + v.y * g.y + v.z * g.z + v.w * g.w;
    }
    sc[m4] = d - qv[m];     // 2*hn.En_m - ||En_m||^2 (||hn||^2 cancels in pair)
  }
  // two complete softmax pairs per lane
  float av[4];
  int mycode = 0;
  {
    const float mx = fmaxf(sc[0], sc[1]);
    const float e0 = expf(sc[0] - mx), e1 = expf(sc[1] - mx);
    const float rs = 1.0f / (e0 + e1);
    av[0] = e0 * rs; av[1] = e1 * rs;
    mycode |= (e1 > e0) ? (1 << (2 * pg)) : 0;
  }
  {
    const float mx = fmaxf(sc[2], sc[3]);
    const float e0 = expf(sc[2] - mx), e1 = expf(sc[3] - mx);
    const float rs = 1.0f / (e0 + e1);
    av[2] = e0 * rs; av[3] = e1 * rs;
    mycode |= (e1 > e0) ? (1 << (2 * pg + 1)) : 0;
  }
  const int t = wtok + tk;
  const int mk = mask[t];
  const float msk = (mk == 1) ? 1.0f : 0.0f;
  ((float4*)(Aout + (size_t)t * MCODES))[pg] =
      make_float4(av[0] * msk, av[1] * msk, av[2] * msk, av[3] * msk);
#pragma unroll
  for (int m = 1; m <= 4; m <<= 1) mycode |= __shfl_xor(mycode, m);
  if (pg == 0) code_out[t] = (mk == 1) ? (float)mycode : 0.0f;
}

// ---------------------------------------------------------------------------
// inv: quantized = A' @ C + b_inv.  C columns (e-pair) resident in registers.
// ---------------------------------------------------------------------------
__global__ __launch_bounds__(256)
void inv_kernel(const float* __restrict__ Ap, const float* __restrict__ Cw,
                const float* __restrict__ b_inv, float* __restrict__ qout) {
  const int tid = threadIdx.x;
  const int w = tid >> 6;
  const int lane = tid & 63;
  const int ep = w * 64 + lane;      // e-pair index; e = 2*ep
  const int tile = blockIdx.x * 64;
  float2 c[32];
#pragma unroll
  for (int m = 0; m < 32; ++m) c[m] = ((const float2*)(Cw + m * EMB))[ep];
  const float2 bi = ((const float2*)b_inv)[ep];
  for (int tt = 0; tt < 64; ++tt) {
    const int t = tile + tt;
    const float4* a4 = (const float4*)(Ap + (size_t)t * 32);   // uniform address
    float accx = bi.x, accy = bi.y;
#pragma unroll
    for (int k = 0; k < 8; ++k) {
      const float4 a = a4[k];
      accx += a.x * c[4 * k].x + a.y * c[4 * k + 1].x + a.z * c[4 * k + 2].x + a.w * c[4 * k + 3].x;
      accy += a.x * c[4 * k].y + a.y * c[4 * k + 1].y + a.z * c[4 * k + 2].y + a.w * c[4 * k + 3].y;
    }
    ((float2*)(qout + (size_t)t * EMB))[ep] = make_float2(accx, accy);
  }
}

// ---------------------------------------------------------------------------
extern "C" void kernel_launch(void* const* d_in, const int* in_sizes, int n_in,
                              void* d_out, int out_size, void* d_ws, size_t ws_size,
                              hipStream_t stream) {
  (void)n_in; (void)out_size; (void)ws_size;
  const float* h      = (const float*)d_in[0];
  const int*   mask   = (const int*)  d_in[1];
  const float* W_proj = (const float*)d_in[2];
  const float* b_proj = (const float*)d_in[3];
  const float* W_inv  = (const float*)d_in[4];
  const float* b_inv  = (const float*)d_in[5];
  const float* emb    = (const float*)d_in[6];

  const int N = in_sizes[1];          // 65536 tokens (32*2048)

  float* quant    = (float*)d_out;                    // [N][512]
  float* code_out = quant + (size_t)N * EMB;          // [N] as float
  float* loss_out = code_out + N;                     // [1]

  float* ws = (float*)d_ws;
  float* Ap = ws;                                     // [N][32] masked soft assign
  float* Cw = Ap + (size_t)N * MCODES;                // [32][512] = En @ W_inv
  float* G  = Cw + MCODES * EMB;                      // [32][32]  = 2*En
  float* qv = G + MCODES * VQ;                        // [32]      = ||En||^2

  prep_kernel<<<MCODES, 256, 0, stream>>>(emb, W_inv, Cw, G, qv, loss_out);
  proj_kernel<<<N / 32, 256, 0, stream>>>(h, mask, W_proj, b_proj, G, qv, Ap, code_out);
  inv_kernel<<<N / 64, 256, 0, stream>>>(Ap, Cw, b_inv, quant);
}

// Round 12
// 140.473 us; speedup vs baseline: 1.1098x; 1.1098x over previous
//
#include <hip/hip_runtime.h>
#include <math.h>

#define EMB 512
#define VQ 32
#define MCODES 32   // 2*LOG2
#define EPS 1e-8f

#define ACC4(A, V)                                                        \
    A.x += V.x * w0.x; A.x += V.y * w1.x; A.x += V.z * w2.x; A.x += V.w * w3.x; \
    A.y += V.x * w0.y; A.y += V.y * w1.y; A.y += V.z * w2.y; A.y += V.w * w3.y; \
    A.z += V.x * w0.z; A.z += V.y * w1.z; A.z += V.z * w2.z; A.z += V.w * w3.z; \
    A.w += V.x * w0.w; A.w += V.y * w1.w; A.w += V.z * w2.w; A.w += V.w * w3.w;

// ---------------------------------------------------------------------------
// prep: normalize codebook rows, G = 2*En, q = ||En||^2, C = En @ W_inv
// ---------------------------------------------------------------------------
__global__ __launch_bounds__(256)
void prep_kernel(const float* __restrict__ emb, const float* __restrict__ W_inv,
                 float* __restrict__ Cw, float* __restrict__ G, float* __restrict__ qv,
                 float* __restrict__ loss_out) {
  const int b = blockIdx.x;
  const int tid = threadIdx.x;
  __shared__ float En_s[VQ];
  float ss = 0.f;
#pragma unroll
  for (int d = 0; d < VQ; ++d) { float v = emb[b * VQ + d]; ss += v * v; }
  const float inv = 1.0f / (sqrtf(ss) + EPS);
  if (tid < VQ) En_s[tid] = emb[b * VQ + tid] * inv;
  __syncthreads();
  float a0 = 0.f, a1 = 0.f;
#pragma unroll 8
  for (int d = 0; d < VQ; ++d) {
    const float en = En_s[d];
    const float2 wv = ((const float2*)(W_inv + d * EMB))[tid];
    a0 += en * wv.x;
    a1 += en * wv.y;
  }
  ((float2*)(Cw + b * EMB))[tid] = make_float2(a0, a1);
  if (tid < VQ) G[b * VQ + tid] = 2.0f * En_s[tid];
  if (tid == 0) {
    float qq = 0.f;
#pragma unroll
    for (int d = 0; d < VQ; ++d) qq += En_s[d] * En_s[d];
    qv[b] = qq;
    if (b == 0) loss_out[0] = 0.0f;   // vq_loss
  }
}

// ---------------------------------------------------------------------------
// projA: R9 control (W from global/L1 — suspected L1-thrash bottleneck).
// Handles tokens [0, N/2).
// ---------------------------------------------------------------------------
__global__ __launch_bounds__(256)
void projA_kernel(const float* __restrict__ h, const int* __restrict__ mask,
                  const float* __restrict__ W_proj, const float* __restrict__ b_proj,
                  const float* __restrict__ G, const float* __restrict__ qv,
                  float* __restrict__ Aout, float* __restrict__ code_out) {
  const int tid = threadIdx.x;
  const int wv = tid >> 6;
  const int lane = tid & 63;
  const int slot = lane >> 3;
  const int dg = lane & 7;
  const int tile = blockIdx.x * 32;
  __shared__ float hp_s[4][32][36];

  const float4* __restrict__ h4 = (const float4*)h;
  const float4* __restrict__ W4 = (const float4*)W_proj;

  const int e4base = wv * 32;
  const float4* hr0 = h4 + (size_t)(tile + slot) * (EMB / 4) + e4base;
  const float4* hr1 = hr0 + 8 * (EMB / 4);
  const float4* hr2 = hr1 + 8 * (EMB / 4);
  const float4* hr3 = hr2 + 8 * (EMB / 4);

  float4 a0 = make_float4(0.f, 0.f, 0.f, 0.f), a1 = a0, a2 = a0, a3 = a0;

  for (int e4 = 0; e4 < 32; ++e4) {
    const int eb = (e4base + e4) << 2;
    const float4 w0 = W4[(eb + 0) * 8 + dg];
    const float4 w1 = W4[(eb + 1) * 8 + dg];
    const float4 w2 = W4[(eb + 2) * 8 + dg];
    const float4 w3 = W4[(eb + 3) * 8 + dg];
    const float4 v0 = hr0[e4];
    const float4 v1 = hr1[e4];
    const float4 v2 = hr2[e4];
    const float4 v3 = hr3[e4];
    ACC4(a0, v0) ACC4(a1, v1) ACC4(a2, v2) ACC4(a3, v3)
  }
  *(float4*)&hp_s[wv][slot     ][dg * 4] = a0;
  *(float4*)&hp_s[wv][slot +  8][dg * 4] = a1;
  *(float4*)&hp_s[wv][slot + 16][dg * 4] = a2;
  *(float4*)&hp_s[wv][slot + 24][dg * 4] = a3;
  __syncthreads();

  if (tid < 32) {
    const int t = tile + tid;
    const float4* bp4 = (const float4*)b_proj;
    float4 hp[8];
    float ssum = 0.f;
#pragma unroll
    for (int k = 0; k < 8; ++k) {
      float4 p0 = *(const float4*)&hp_s[0][tid][k * 4];
      const float4 p1 = *(const float4*)&hp_s[1][tid][k * 4];
      const float4 p2 = *(const float4*)&hp_s[2][tid][k * 4];
      const float4 p3 = *(const float4*)&hp_s[3][tid][k * 4];
      const float4 b = bp4[k];
      float4 v;
      v.x = ((p0.x + p1.x) + p2.x) + p3.x + b.x;
      v.y = ((p0.y + p1.y) + p2.y) + p3.y + b.y;
      v.z = ((p0.z + p1.z) + p2.z) + p3.z + b.z;
      v.w = ((p0.w + p1.w) + p2.w) + p3.w + b.w;
      hp[k] = v;
      ssum += v.x * v.x + v.y * v.y + v.z * v.z + v.w * v.w;
    }
    const float inv = 1.0f / (sqrtf(ssum) + EPS);
#pragma unroll
    for (int k = 0; k < 8; ++k) {
      hp[k].x *= inv; hp[k].y *= inv; hp[k].z *= inv; hp[k].w *= inv;
    }
    const float4* G4 = (const float4*)G;
    float av[32];
    int code = 0;
#pragma unroll
    for (int g = 0; g < 16; ++g) {
      float d0 = 0.f, d1 = 0.f;
#pragma unroll
      for (int k = 0; k < 8; ++k) {
        const float4 g0 = G4[(2 * g) * 8 + k];
        const float4 g1 = G4[(2 * g + 1) * 8 + k];
        const float4 hv = hp[k];
        d0 += hv.x * g0.x + hv.y * g0.y + hv.z * g0.z + hv.w * g0.w;
        d1 += hv.x * g1.x + hv.y * g1.y + hv.z * g1.z + hv.w * g1.w;
      }
      const float s0 = d0 - qv[2 * g];
      const float s1 = d1 - qv[2 * g + 1];
      const float mx = fmaxf(s0, s1);
      const float e0 = expf(s0 - mx);
      const float e1 = expf(s1 - mx);
      const float rs = 1.0f / (e0 + e1);
      av[2 * g] = e0 * rs;
      av[2 * g + 1] = e1 * rs;
      code |= (e1 > e0) ? (1 << g) : 0;
    }
    const int mk = mask[t];
    const float msk = (mk == 1) ? 1.0f : 0.0f;
    float4* Ao = (float4*)(Aout + (size_t)t * MCODES);
#pragma unroll
    for (int k = 0; k < 8; ++k) {
      Ao[k] = make_float4(av[4 * k] * msk, av[4 * k + 1] * msk,
                          av[4 * k + 2] * msk, av[4 * k + 3] * msk);
    }
    code_out[t] = (mk == 1) ? (float)code : 0.0f;
  }
}

// ---------------------------------------------------------------------------
// projB: W staged ONCE into LDS (pitch-9 float4 -> <=2-way banking = free),
// 512 thr = 8 waves, 64 tokens/block, intra-wave split-K (shfl combine),
// h direct loads with ring-2 prefetch. Handles tokens [tbase, tbase+N/2).
// Theory: W (64KB) thrashes the 32KB L1 in all prior variants -> ~200cy
// dependent stalls per iteration; LDS serves W at ~12cy pipelined.
// ---------------------------------------------------------------------------
__global__ __launch_bounds__(512)
void projB_kernel(const float* __restrict__ h, const int* __restrict__ mask,
                  const float* __restrict__ W_proj, const float* __restrict__ b_proj,
                  const float* __restrict__ G, const float* __restrict__ qv,
                  float* __restrict__ Aout, float* __restrict__ code_out, int tbase) {
  const int tid = threadIdx.x;
  const int w = tid >> 6;        // wave 0..7
  const int lane = tid & 63;
  const int kq = lane >> 4;      // 0..3 : K-quarter
  const int s = (lane >> 3) & 1; // 0..1 : token-group
  const int dg = lane & 7;       // 0..7 : out-dims 4*dg..4*dg+3
  const int wtok = tbase + blockIdx.x * 64 + w * 8;

  __shared__ float4 Wlds[512 * 9];   // [e][dg] pitch 9 -> 73728 B

  // cooperative W stage: 4096 float4 over 512 threads
  const float4* __restrict__ W4 = (const float4*)W_proj;
#pragma unroll
  for (int i = 0; i < 8; ++i) {
    const int k = tid * 8 + i;               // 0..4095
    Wlds[(k >> 3) * 9 + (k & 7)] = W4[k];
  }
  __syncthreads();

  const float4* __restrict__ h4 = (const float4*)h;
  const int e4base = kq * 32;
  const float4* hr0 = h4 + (size_t)(wtok + 4 * s + 0) * (EMB / 4) + e4base;
  const float4* hr1 = hr0 + (EMB / 4);
  const float4* hr2 = hr1 + (EMB / 4);
  const float4* hr3 = hr2 + (EMB / 4);

  float4 acc0 = make_float4(0.f, 0.f, 0.f, 0.f), acc1 = acc0, acc2 = acc0, acc3 = acc0;

  // ring-2 h prefetch
  float4 va[2][4];
  va[0][0] = hr0[0]; va[0][1] = hr1[0]; va[0][2] = hr2[0]; va[0][3] = hr3[0];
  va[1][0] = hr0[1]; va[1][1] = hr1[1]; va[1][2] = hr2[1]; va[1][3] = hr3[1];

#pragma unroll 2
  for (int e4 = 0; e4 < 32; ++e4) {
    const int cur = e4 & 1;
    const float4 v0 = va[cur][0];
    const float4 v1 = va[cur][1];
    const float4 v2 = va[cur][2];
    const float4 v3 = va[cur][3];
    if (e4 + 2 < 32) {
      va[cur][0] = hr0[e4 + 2]; va[cur][1] = hr1[e4 + 2];
      va[cur][2] = hr2[e4 + 2]; va[cur][3] = hr3[e4 + 2];
    }
    const int e = (e4base + e4) << 2;
    const float4 w0 = Wlds[(e + 0) * 9 + dg];
    const float4 w1 = Wlds[(e + 1) * 9 + dg];
    const float4 w2 = Wlds[(e + 2) * 9 + dg];
    const float4 w3 = Wlds[(e + 3) * 9 + dg];
    ACC4(acc0, v0) ACC4(acc1, v1) ACC4(acc2, v2) ACC4(acc3, v3)
  }

  // combine split-K partials across kq lanes
#define CMB(A) \
  A.x += __shfl_xor(A.x, 16); A.y += __shfl_xor(A.y, 16); \
  A.z += __shfl_xor(A.z, 16); A.w += __shfl_xor(A.w, 16); \
  A.x += __shfl_xor(A.x, 32); A.y += __shfl_xor(A.y, 32); \
  A.z += __shfl_xor(A.z, 32); A.w += __shfl_xor(A.w, 32);
  CMB(acc0) CMB(acc1) CMB(acc2) CMB(acc3)
#undef CMB

  const float4 bp = ((const float4*)b_proj)[dg];
  acc0.x += bp.x; acc0.y += bp.y; acc0.z += bp.z; acc0.w += bp.w;
  acc1.x += bp.x; acc1.y += bp.y; acc1.z += bp.z; acc1.w += bp.w;
  acc2.x += bp.x; acc2.y += bp.y; acc2.z += bp.z; acc2.w += bp.w;
  acc3.x += bp.x; acc3.y += bp.y; acc3.z += bp.z; acc3.w += bp.w;

  float ss0 = acc0.x * acc0.x + acc0.y * acc0.y + acc0.z * acc0.z + acc0.w * acc0.w;
  float ss1 = acc1.x * acc1.x + acc1.y * acc1.y + acc1.z * acc1.z + acc1.w * acc1.w;
  float ss2 = acc2.x * acc2.x + acc2.y * acc2.y + acc2.z * acc2.z + acc2.w * acc2.w;
  float ss3 = acc3.x * acc3.x + acc3.y * acc3.y + acc3.z * acc3.z + acc3.w * acc3.w;
#pragma unroll
  for (int m = 1; m <= 4; m <<= 1) {
    ss0 += __shfl_xor(ss0, m); ss1 += __shfl_xor(ss1, m);
    ss2 += __shfl_xor(ss2, m); ss3 += __shfl_xor(ss3, m);
  }
  const float i0 = 1.0f / (sqrtf(ss0) + EPS);
  const float i1 = 1.0f / (sqrtf(ss1) + EPS);
  const float i2 = 1.0f / (sqrtf(ss2) + EPS);
  const float i3 = 1.0f / (sqrtf(ss3) + EPS);
  acc0.x *= i0; acc0.y *= i0; acc0.z *= i0; acc0.w *= i0;
  acc1.x *= i1; acc1.y *= i1; acc1.z *= i1; acc1.w *= i1;
  acc2.x *= i2; acc2.y *= i2; acc2.z *= i2; acc2.w *= i2;
  acc3.x *= i3; acc3.y *= i3; acc3.z *= i3; acc3.w *= i3;

  __syncthreads();   // all waves finished reading Wlds -> safe to reuse as scratch

  float* scratch = (float*)&Wlds[0] + (size_t)w * 320;   // per-wave [8 tok][40]
  if (kq == 0) {
    *(float4*)&scratch[(4 * s + 0) * 40 + 4 * dg] = acc0;
    *(float4*)&scratch[(4 * s + 1) * 40 + 4 * dg] = acc1;
    *(float4*)&scratch[(4 * s + 2) * 40 + 4 * dg] = acc2;
    *(float4*)&scratch[(4 * s + 3) * 40 + 4 * dg] = acc3;
  }
  const int tk = lane >> 3;
  const int pg = lane & 7;
  float4 hn[8];
#pragma unroll
  for (int k = 0; k < 8; ++k) hn[k] = *(const float4*)&scratch[tk * 40 + 4 * k];

  const float4* G4 = (const float4*)G;
  float sc[4];
#pragma unroll
  for (int m4 = 0; m4 < 4; ++m4) {
    const int m = 4 * pg + m4;
    float d = 0.f;
#pragma unroll
    for (int k = 0; k < 8; ++k) {
      const float4 g = G4[m * 8 + k];
      const float4 v = hn[k];
      d += v.x * g.x + v.y * g.y + v.z * g.z + v.w * g.w;
    }
    sc[m4] = d - qv[m];
  }
  float av[4];
  int mycode = 0;
  {
    const float mx = fmaxf(sc[0], sc[1]);
    const float e0 = expf(sc[0] - mx), e1 = expf(sc[1] - mx);
    const float rs = 1.0f / (e0 + e1);
    av[0] = e0 * rs; av[1] = e1 * rs;
    mycode |= (e1 > e0) ? (1 << (2 * pg)) : 0;
  }
  {
    const float mx = fmaxf(sc[2], sc[3]);
    const float e0 = expf(sc[2] - mx), e1 = expf(sc[3] - mx);
    const float rs = 1.0f / (e0 + e1);
    av[2] = e0 * rs; av[3] = e1 * rs;
    mycode |= (e1 > e0) ? (1 << (2 * pg + 1)) : 0;
  }
  const int t = wtok + tk;
  const int mk = mask[t];
  const float msk = (mk == 1) ? 1.0f : 0.0f;
  ((float4*)(Aout + (size_t)t * MCODES))[pg] =
      make_float4(av[0] * msk, av[1] * msk, av[2] * msk, av[3] * msk);
#pragma unroll
  for (int m = 1; m <= 4; m <<= 1) mycode |= __shfl_xor(mycode, m);
  if (pg == 0) code_out[t] = (mk == 1) ? (float)mycode : 0.0f;
}

// ---------------------------------------------------------------------------
// inv: quantized = A' @ C + b_inv.  C columns (e-pair) resident in registers.
// ---------------------------------------------------------------------------
__global__ __launch_bounds__(256)
void inv_kernel(const float* __restrict__ Ap, const float* __restrict__ Cw,
                const float* __restrict__ b_inv, float* __restrict__ qout) {
  const int tid = threadIdx.x;
  const int w = tid >> 6;
  const int lane = tid & 63;
  const int ep = w * 64 + lane;
  const int tile = blockIdx.x * 64;
  float2 c[32];
#pragma unroll
  for (int m = 0; m < 32; ++m) c[m] = ((const float2*)(Cw + m * EMB))[ep];
  const float2 bi = ((const float2*)b_inv)[ep];
  for (int tt = 0; tt < 64; ++tt) {
    const int t = tile + tt;
    const float4* a4 = (const float4*)(Ap + (size_t)t * 32);
    float accx = bi.x, accy = bi.y;
#pragma unroll
    for (int k = 0; k < 8; ++k) {
      const float4 a = a4[k];
      accx += a.x * c[4 * k].x + a.y * c[4 * k + 1].x + a.z * c[4 * k + 2].x + a.w * c[4 * k + 3].x;
      accy += a.x * c[4 * k].y + a.y * c[4 * k + 1].y + a.z * c[4 * k + 2].y + a.w * c[4 * k + 3].y;
    }
    ((float2*)(qout + (size_t)t * EMB))[ep] = make_float2(accx, accy);
  }
}

// ---------------------------------------------------------------------------
extern "C" void kernel_launch(void* const* d_in, const int* in_sizes, int n_in,
                              void* d_out, int out_size, void* d_ws, size_t ws_size,
                              hipStream_t stream) {
  (void)n_in; (void)out_size; (void)ws_size;
  const float* h      = (const float*)d_in[0];
  const int*   mask   = (const int*)  d_in[1];
  const float* W_proj = (const float*)d_in[2];
  const float* b_proj = (const float*)d_in[3];
  const float* W_inv  = (const float*)d_in[4];
  const float* b_inv  = (const float*)d_in[5];
  const float* emb    = (const float*)d_in[6];

  const int N = in_sizes[1];          // 65536 tokens
  const int N2 = N / 2;

  float* quant    = (float*)d_out;
  float* code_out = quant + (size_t)N * EMB;
  float* loss_out = code_out + N;

  float* ws = (float*)d_ws;
  float* Ap = ws;                                     // [N][32]
  float* Cw = Ap + (size_t)N * MCODES;                // [32][512]
  float* G  = Cw + MCODES * EMB;                      // [32][32]
  float* qv = G + MCODES * VQ;                        // [32]

  prep_kernel<<<MCODES, 256, 0, stream>>>(emb, W_inv, Cw, G, qv, loss_out);
  projA_kernel<<<N2 / 32, 256, 0, stream>>>(h, mask, W_proj, b_proj, G, qv, Ap, code_out);
  projB_kernel<<<N2 / 64, 512, 0, stream>>>(h, mask, W_proj, b_proj, G, qv, Ap, code_out, N2);
  inv_kernel<<<N / 64, 256, 0, stream>>>(Ap, Cw, b_inv, quant);
}